// Round 1
// baseline (387.044 us; speedup 1.0000x reference)
//
#include <hip/hip_runtime.h>
#include <cstdint>

#define N_TOK 4096
#define DMODEL 1024
#define DFFC 2048
#define NEXP 8
#define NR (N_TOK*2)      /* 8192 expanded rows (top-2) */
#define NRP (NR+128)      /* padded for tile overrun */

typedef unsigned short ushort_t;
typedef __attribute__((ext_vector_type(8))) short short8v;   // 8 bf16 (4 VGPRs)
typedef __attribute__((ext_vector_type(4))) float float4v;   // MFMA C/D

__device__ __forceinline__ ushort_t f2bf(float f){
  union { float f; unsigned u; } v; v.f = f;
  unsigned r = v.u + 0x7fffu + ((v.u >> 16) & 1u);
  return (ushort_t)(r >> 16);
}

__device__ __forceinline__ void gl_lds16(const void* g, void* l){
  __builtin_amdgcn_global_load_lds((const __attribute__((address_space(1))) char*)g,
                                   (__attribute__((address_space(3))) char*)l, 16, 0, 0);
}

// ---------------- router: logits (fp32, exact output), softmax, top-2, scatter ----------------
__global__ void router_k(const float* __restrict__ x, const float* __restrict__ Wg,
                         const float* __restrict__ bg, float* __restrict__ logits,
                         int* __restrict__ cnt, int* __restrict__ elist, float* __restrict__ wslot){
  int t = blockIdx.x;
  int l = threadIdx.x;
  const float* xr = x + (size_t)t * DMODEL;
  float acc[NEXP];
  #pragma unroll
  for (int e=0;e<NEXP;e++) acc[e]=0.f;
  for (int i=l;i<DMODEL;i+=64){
    float xv = xr[i];
    const float* wr = Wg + (size_t)i*NEXP;
    #pragma unroll
    for (int e=0;e<NEXP;e++) acc[e] += xv*wr[e];
  }
  #pragma unroll
  for (int e=0;e<NEXP;e++){
    float v = acc[e];
    #pragma unroll
    for (int s=32;s>0;s>>=1) v += __shfl_xor(v,s);
    acc[e]=v;
  }
  if (l==0){
    float lg[NEXP]; float m=-1e30f;
    #pragma unroll
    for (int e=0;e<NEXP;e++){ lg[e]=acc[e]+bg[e]; m = fmaxf(m,lg[e]); }
    float p[NEXP];
    #pragma unroll
    for (int e=0;e<NEXP;e++) p[e]=__expf(lg[e]-m);
    int e0=0;
    #pragma unroll
    for (int e=1;e<NEXP;e++) if (p[e]>p[e0]) e0=e;      // strict > : lower idx wins ties (matches top_k)
    int e1=(e0==0)?1:0;
    #pragma unroll
    for (int e=0;e<NEXP;e++) if (e!=e0 && p[e]>p[e1]) e1=e;
    float ps=p[e0]+p[e1];
    float w0=p[e0]/ps, w1=p[e1]/ps;
    #pragma unroll
    for (int e=0;e<NEXP;e++) logits[(size_t)t*NEXP+e]=lg[e];
    wslot[t*2+0]=w0; wslot[t*2+1]=w1;
    int p0=atomicAdd(&cnt[e0],1); elist[e0*N_TOK+p0]=t*2+0;
    int p1=atomicAdd(&cnt[e1],1); elist[e1*N_TOK+p1]=t*2+1;
  }
}

__global__ void scan_k(const int* __restrict__ cnt, int* __restrict__ offs){
  if (threadIdx.x==0 && blockIdx.x==0){
    int s=0;
    for (int e=0;e<NEXP;e++){ offs[e]=s; s+=cnt[e]; }
    offs[NEXP]=s;
  }
}

// ---------------- gather tokens into compacted bf16 Xg rows ----------------
__global__ void gather_k(const float* __restrict__ x, const int* __restrict__ cnt,
                         const int* __restrict__ offs, const int* __restrict__ elist,
                         const float* __restrict__ wslot,
                         ushort_t* __restrict__ Xg, int* __restrict__ rowslot, float* __restrict__ roww){
  int e = blockIdx.y; int i = blockIdx.x;
  if (i >= cnt[e]) return;
  int entry = elist[e*N_TOK+i];
  int t = entry>>1;
  int r = offs[e]+i;
  const float4* xr = (const float4*)(x + (size_t)t*DMODEL);
  ushort_t* dst = Xg + (size_t)r*DMODEL;
  int tid = threadIdx.x;
  float4 v = xr[tid];
  ushort_t o0=f2bf(v.x), o1=f2bf(v.y), o2=f2bf(v.z), o3=f2bf(v.w);
  ushort4 o; o.x=o0; o.y=o1; o.z=o2; o.w=o3;
  *(ushort4*)(dst + tid*4) = o;
  if (tid==0){ rowslot[r]=entry; roww[r]=wslot[entry]; }
}

// ---------------- weight transpose + fp32->bf16: [k][f] -> [f][k] ----------------
__global__ void transpose_k(const float* __restrict__ Ww, const float* __restrict__ Wv,
                            const float* __restrict__ Wo,
                            ushort_t* __restrict__ WwT, ushort_t* __restrict__ WvT,
                            ushort_t* __restrict__ WoT){
  __shared__ ushort_t tile[64][65];
  int z = blockIdx.z;
  const float* src; ushort_t* dst; int K, F;
  if (z < 8)      { src = Ww + (size_t)z*DMODEL*DFFC;     dst = WwT + (size_t)z*DFFC*DMODEL;     K=DMODEL; F=DFFC; }
  else if (z < 16){ src = Wv + (size_t)(z-8)*DMODEL*DFFC; dst = WvT + (size_t)(z-8)*DFFC*DMODEL; K=DMODEL; F=DFFC; }
  else            { src = Wo + (size_t)(z-16)*DFFC*DMODEL; dst = WoT + (size_t)(z-16)*DMODEL*DFFC; K=DFFC; F=DMODEL; }
  int f0 = blockIdx.x*64, k0 = blockIdx.y*64;
  if (f0 >= F || k0 >= K) return;
  int tid = threadIdx.x;
  #pragma unroll
  for (int it=0; it<16; ++it){
    int idx = it*256 + tid;
    int r = idx>>6, c = idx&63;
    tile[r][c] = f2bf(src[(size_t)(k0+r)*F + f0+c]);
  }
  __syncthreads();
  #pragma unroll
  for (int it=0; it<8; ++it){
    int idx = it*256 + tid;
    int c = idx>>5, rp = (idx&31)*2;
    ushort2 v; v.x = tile[rp][c]; v.y = tile[rp+1][c];
    *(ushort2*)&dst[(size_t)(f0+c)*K + k0+rp] = v;
  }
}

// ---------------- GEMM1: H = silu(Xg@Ww + bw) * (Xg@Wv + bv), dual-acc, grouped ----------------
__global__ __launch_bounds__(256,2) void gemm1_k(const ushort_t* __restrict__ Xg,
    const ushort_t* __restrict__ WwT, const ushort_t* __restrict__ WvT,
    const float* __restrict__ bw, const float* __restrict__ bv,
    const int* __restrict__ cnt, const int* __restrict__ offs,
    ushort_t* __restrict__ H){
  __shared__ ushort_t As[128*64];
  __shared__ ushort_t Bs[2][128*64];
  int e  = blockIdx.y >> 5;
  int mt = blockIdx.y & 31;
  int cnte = cnt[e];
  if (mt*128 >= cnte) return;
  int row0 = offs[e] + mt*128;
  int f0 = blockIdx.x * 128;
  const ushort_t* A0  = Xg  + (size_t)row0*DMODEL;
  const ushort_t* B0w = WwT + (size_t)e*DFFC*DMODEL + (size_t)f0*DMODEL;
  const ushort_t* B0v = WvT + (size_t)e*DFFC*DMODEL + (size_t)f0*DMODEL;
  int tid = threadIdx.x;
  int w = tid>>6, l = tid&63;
  int lrow = l>>3, lk = (l&7)*8;
  int wr = w>>1, wc = w&1;
  float4v accw[4][4], accv[4][4];
  #pragma unroll
  for (int m=0;m<4;m++)
    #pragma unroll
    for (int n=0;n<4;n++){ accw[m][n]=(float4v){0,0,0,0}; accv[m][n]=(float4v){0,0,0,0}; }
  for (int kt=0; kt<DMODEL/64; ++kt){
    int k0 = kt*64;
    #pragma unroll
    for (int i=0;i<4;i++){
      int rb = w*32 + i*8;
      gl_lds16(A0  + (size_t)(rb+lrow)*DMODEL + k0 + lk, &As[rb*64]);
      gl_lds16(B0w + (size_t)(rb+lrow)*DMODEL + k0 + lk, &Bs[0][rb*64]);
      gl_lds16(B0v + (size_t)(rb+lrow)*DMODEL + k0 + lk, &Bs[1][rb*64]);
    }
    __syncthreads();
    #pragma unroll
    for (int ks=0; ks<2; ++ks){
      short8v a[4];
      #pragma unroll
      for (int m=0;m<4;m++)
        a[m] = *(const short8v*)&As[(wr*64 + m*16 + (l&15))*64 + ks*32 + (l>>4)*8];
      #pragma unroll
      for (int n=0;n<4;n++){
        int boff = (wc*64 + n*16 + (l&15))*64 + ks*32 + (l>>4)*8;
        short8v b0 = *(const short8v*)&Bs[0][boff];
        short8v b1 = *(const short8v*)&Bs[1][boff];
        #pragma unroll
        for (int m=0;m<4;m++){
          accw[m][n] = __builtin_amdgcn_mfma_f32_16x16x32_bf16(a[m], b0, accw[m][n], 0,0,0);
          accv[m][n] = __builtin_amdgcn_mfma_f32_16x16x32_bf16(a[m], b1, accv[m][n], 0,0,0);
        }
      }
    }
    __syncthreads();
  }
  int rows_valid = cnte - mt*128; if (rows_valid>128) rows_valid=128;
  #pragma unroll
  for (int m=0;m<4;m++){
    #pragma unroll
    for (int r=0;r<4;r++){
      int row_local = wr*64 + m*16 + (l>>4)*4 + r;
      if (row_local < rows_valid){
        size_t hbase = (size_t)(row0 + row_local)*DFFC;
        #pragma unroll
        for (int n=0;n<4;n++){
          int f = f0 + wc*64 + n*16 + (l&15);
          float wx = accw[m][n][r] + bw[e*DFFC + f];
          float vx = accv[m][n][r] + bv[e*DFFC + f];
          float h = (wx / (1.f + __expf(-wx))) * vx;
          H[hbase + f] = f2bf(h);
        }
      }
    }
  }
}

// ---------------- GEMM2: Y[slot] = w * (H@Wo + bo), grouped ----------------
__global__ __launch_bounds__(256,2) void gemm2_k(const ushort_t* __restrict__ H,
    const ushort_t* __restrict__ WoT, const float* __restrict__ bo,
    const int* __restrict__ cnt, const int* __restrict__ offs,
    const int* __restrict__ rowslot, const float* __restrict__ roww,
    float* __restrict__ Y){
  __shared__ ushort_t As[128*64];
  __shared__ ushort_t Bs[128*64];
  int e  = blockIdx.y >> 5;
  int mt = blockIdx.y & 31;
  int cnte = cnt[e];
  if (mt*128 >= cnte) return;
  int row0 = offs[e] + mt*128;
  int d0 = blockIdx.x * 128;
  const ushort_t* A0 = H   + (size_t)row0*DFFC;
  const ushort_t* B0 = WoT + (size_t)e*DMODEL*DFFC + (size_t)d0*DFFC;
  int tid = threadIdx.x;
  int w = tid>>6, l = tid&63;
  int lrow = l>>3, lk = (l&7)*8;
  int wr = w>>1, wc = w&1;
  float4v acc[4][4];
  #pragma unroll
  for (int m=0;m<4;m++)
    #pragma unroll
    for (int n=0;n<4;n++) acc[m][n]=(float4v){0,0,0,0};
  for (int kt=0; kt<DFFC/64; ++kt){
    int k0 = kt*64;
    #pragma unroll
    for (int i=0;i<4;i++){
      int rb = w*32 + i*8;
      gl_lds16(A0 + (size_t)(rb+lrow)*DFFC + k0 + lk, &As[rb*64]);
      gl_lds16(B0 + (size_t)(rb+lrow)*DFFC + k0 + lk, &Bs[rb*64]);
    }
    __syncthreads();
    #pragma unroll
    for (int ks=0; ks<2; ++ks){
      short8v a[4];
      #pragma unroll
      for (int m=0;m<4;m++)
        a[m] = *(const short8v*)&As[(wr*64 + m*16 + (l&15))*64 + ks*32 + (l>>4)*8];
      #pragma unroll
      for (int n=0;n<4;n++){
        short8v b = *(const short8v*)&Bs[(wc*64 + n*16 + (l&15))*64 + ks*32 + (l>>4)*8];
        #pragma unroll
        for (int m=0;m<4;m++)
          acc[m][n] = __builtin_amdgcn_mfma_f32_16x16x32_bf16(a[m], b, acc[m][n], 0,0,0);
      }
    }
    __syncthreads();
  }
  int rows_valid = cnte - mt*128; if (rows_valid>128) rows_valid=128;
  #pragma unroll
  for (int m=0;m<4;m++){
    #pragma unroll
    for (int r=0;r<4;r++){
      int row_local = wr*64 + m*16 + (l>>4)*4 + r;
      if (row_local < rows_valid){
        int gr = row0 + row_local;
        int slot = rowslot[gr];
        float wgt = roww[gr];
        size_t ybase = (size_t)slot*DMODEL;
        #pragma unroll
        for (int n=0;n<4;n++){
          int d = d0 + wc*64 + n*16 + (l&15);
          Y[ybase + d] = wgt * (acc[m][n][r] + bo[e*DMODEL + d]);
        }
      }
    }
  }
}

// ---------------- combine: final[t] = Y[2t] + Y[2t+1] ----------------
__global__ void combine_k(const float* __restrict__ Y, float* __restrict__ out){
  int idx = blockIdx.x*blockDim.x + threadIdx.x;   // 1M threads, one float4 each
  const float4* y4 = (const float4*)Y;
  float4* o4 = (float4*)out;
  int t = idx >> 8;
  int c = idx & 255;
  float4 a = y4[(size_t)(2*t)*(DMODEL/4) + c];
  float4 b = y4[(size_t)(2*t+1)*(DMODEL/4) + c];
  float4 o; o.x=a.x+b.x; o.y=a.y+b.y; o.z=a.z+b.z; o.w=a.w+b.w;
  o4[idx] = o;
}

extern "C" void kernel_launch(void* const* d_in, const int* in_sizes, int n_in,
                              void* d_out, int out_size, void* d_ws, size_t ws_size,
                              hipStream_t stream){
  const float* x   = (const float*)d_in[0];
  const float* Wg  = (const float*)d_in[1];
  const float* bg  = (const float*)d_in[2];
  const float* Ww  = (const float*)d_in[3];
  const float* bwp = (const float*)d_in[4];
  const float* Wv  = (const float*)d_in[5];
  const float* bvp = (const float*)d_in[6];
  const float* Wo  = (const float*)d_in[7];
  const float* bop = (const float*)d_in[8];
  float* out = (float*)d_out;
  float* logits = out + (size_t)N_TOK*DMODEL;

  // ws layout (~186 MB total)
  char* cur = (char*)d_ws;
  auto alloc = [&](size_t b)->char*{ char* p=cur; cur += (b+255)&~(size_t)255; return p; };
  int*      cnt     = (int*)     alloc(NEXP*4);
  int*      offs    = (int*)     alloc((NEXP+1)*4);
  float*    wslot   = (float*)   alloc((size_t)NR*4);
  int*      elist   = (int*)     alloc((size_t)NEXP*N_TOK*4);
  int*      rowslot = (int*)     alloc((size_t)NRP*4);
  float*    roww    = (float*)   alloc((size_t)NRP*4);
  ushort_t* Xg      = (ushort_t*)alloc((size_t)NRP*DMODEL*2);
  ushort_t* Hb      = (ushort_t*)alloc((size_t)NRP*DFFC*2);
  float*    Y       = (float*)   alloc((size_t)NR*DMODEL*4);
  ushort_t* WwT     = (ushort_t*)alloc((size_t)NEXP*DFFC*DMODEL*2);
  ushort_t* WvT     = (ushort_t*)alloc((size_t)NEXP*DFFC*DMODEL*2);
  ushort_t* WoT     = (ushort_t*)alloc((size_t)NEXP*DMODEL*DFFC*2);
  (void)ws_size; (void)in_sizes; (void)n_in; (void)out_size;

  hipMemsetAsync(cnt, 0, NEXP*4, stream);
  router_k<<<N_TOK, 64, 0, stream>>>(x, Wg, bg, logits, cnt, elist, wslot);
  scan_k<<<1, 1, 0, stream>>>(cnt, offs);
  gather_k<<<dim3(N_TOK, NEXP), 256, 0, stream>>>(x, cnt, offs, elist, wslot, Xg, rowslot, roww);
  transpose_k<<<dim3(32, 32, 24), 256, 0, stream>>>(Ww, Wv, Wo, WwT, WvT, WoT);
  gemm1_k<<<dim3(DFFC/128, NEXP*32), 256, 0, stream>>>(Xg, WwT, WvT, bwp, bvp, cnt, offs, Hb);
  gemm2_k<<<dim3(DMODEL/128, NEXP*32), 256, 0, stream>>>(Hb, WoT, bop, cnt, offs, rowslot, roww, Y);
  combine_k<<<4096, 256, 0, stream>>>(Y, out);
}